// Round 7
// baseline (388.385 us; speedup 1.0000x reference)
//
#include <hip/hip_runtime.h>

// R14: MEGA-KERNEL. Seven configs: profiled components swung 150-190us,
// end-to-end total pinned at 226.6-229.6 -- the timed graph carries a large
// per-launch fixed cost (~15-20us/node), masking kernel-level wins. Fuse all
// four stages into ONE kernel: cast -> QKV gemms -> attn -> proj, separated
// by manual grid barriers (256 blocks x 512 thr = 1 block/CU, all resident
// by construction -> spin barrier safe; threadfence + device-scope atomics
// per guide G12/G16). QKV = proven R4 single-buffer gemm as 2 rounds x 2
// halves; attn = R9 body (60.6us, 16K conflicts) x 2 units; proj = 8-wave
// 128^2 variant (all 512 threads). Barrier counter = last 64B of d_out
// (memset per iter, overwritten by proj post-final-sync).
#define DIM 512
#define NQ 2048
#define MA 2048
#define MS 256
#define QSCALE 0.06375864651f  // 512^-0.5 * log2(e)

typedef __attribute__((ext_vector_type(8))) short bf16x8;
typedef __attribute__((ext_vector_type(4))) float f32x4;
typedef __attribute__((ext_vector_type(16))) float f32x16;

__device__ __forceinline__ ushort f2b(float f) {
    uint u = __float_as_uint(f);
    u = (u + 0x7fffu + ((u >> 16) & 1u)) >> 16;
    return (ushort)u;
}

__device__ __forceinline__ uint pk2bf(float a, float b) {
#if __has_builtin(__builtin_amdgcn_cvt_pk_bf16_f32)
    typedef __attribute__((ext_vector_type(2))) __bf16 bf2;
    bf2 r = __builtin_amdgcn_cvt_pk_bf16_f32(a, b);
    uint u;
    __builtin_memcpy(&u, &r, 4);
    return u;
#else
    return ((__float_as_uint(a) + 0x8000u) >> 16) |
           ((__float_as_uint(b) + 0x8000u) & 0xffff0000u);
#endif
}

__device__ __forceinline__ float fexp2(float x) {
#if __has_builtin(__builtin_amdgcn_exp2f)
    return __builtin_amdgcn_exp2f(x);
#else
    return exp2f(x);
#endif
}

__device__ __forceinline__ void gload16(const ushort* g, ushort* l) {
    __builtin_amdgcn_global_load_lds(
        (const __attribute__((address_space(1))) void*)g,
        (__attribute__((address_space(3))) void*)l, 16, 0, 0);
}

struct GD {
    const ushort* A; const ushort* B; const float* bias; void* out;
    long sB, sO;
    int N, bx, by, blk0, biasrow, scaleq, outf32, pad;
};

struct Args {
    const float *w0, *w1, *w2, *w3, *w4, *w5, *xs, *acs, *scxs;
    ushort* wb;
    GD g0, g1, g2, g3, g4;
    const ushort *qb, *kab, *vta, *ksb, *vts;
    ushort* yb;
    const ushort *pa, *pw;
    const float* pbias;
    float* pout;
    uint* bar;
};

// device-scope grid barrier; all 256 blocks co-resident (1/CU) by construction
__device__ __forceinline__ void gsync(uint* bar, uint target) {
    __syncthreads();
    if (threadIdx.x == 0) {
        __threadfence();                 // release: write back this CU's stores
        atomicAdd(bar, 1u);
        while (__hip_atomic_load(bar, __ATOMIC_ACQUIRE, __HIP_MEMORY_SCOPE_AGENT) < target)
            __builtin_amdgcn_s_sleep(2);
        __threadfence();                 // acquire: invalidate stale L1/L2
    }
    __syncthreads();
}

// ---- phase 0: fused cast, grid-stride, 20 float4 iters/thread ----
__device__ __forceinline__ void cast_phase(const Args& a, int b, int t) {
    int base = b * 512 + t;
#pragma unroll 1
    for (int it = 0; it < 20; it++) {
        int i = it * 131072 + base;  // 2,621,440 float4 total, exact cover
        const float* s;
        int o;
        if (i < 393216) {
            int w = i >> 16;
            s = w < 3 ? (w == 0 ? a.w0 : (w == 1 ? a.w1 : a.w2))
                      : (w == 3 ? a.w3 : (w == 4 ? a.w4 : a.w5));
            o = i & 65535;
        } else if (i < 1441792) { s = a.xs;   o = i - 393216; }
        else if (i < 2490368)   { s = a.acs;  o = i - 1441792; }
        else                    { s = a.scxs; o = i - 2490368; }
        float4 v = ((const float4*)s)[o];
        ushort4 u;
        u.x = f2b(v.x); u.y = f2b(v.y); u.z = f2b(v.z); u.w = f2b(v.w);
        ((ushort4*)a.wb)[i] = u;
    }
}

// ---- phase 1: QKV gemm unit (R4 single-buffer, 256-thr half-block) ----
__device__ __forceinline__ void gemm_qkv(const Args& a, int u, int t,
                                         ushort* At, ushort* Bt, bool active) {
    GD d = a.g0;
    if (u >= a.g1.blk0) d = a.g1;
    if (u >= a.g2.blk0) d = a.g2;
    if (u >= a.g3.blk0) d = a.g3;
    if (u >= a.g4.blk0) d = a.g4;
    int local = u - d.blk0;
    int x = local % d.bx;
    int rem = local / d.bx;
    int y = rem % d.by;
    int z = rem / d.by;

    int wv = t >> 6, ln = t & 63, l = ln & 15, g = ln >> 4;
    int wrow = wv & 1, wcol = wv >> 1;
    int row0 = x * 128, col0 = y * 128;
    int srow = t >> 2;
    int slot = (t & 3) * 8;
    int sko = ((t ^ srow) & 3) * 8;        // XOR-swizzled global k-chunk
    int kc8 = ((g ^ (l & 3)) & 3) * 8;     // reader un-swizzle
    const ushort* Ab = d.A;
    const ushort* Bb = d.B + (size_t)z * d.sB;
    int N = d.N;

    f32x4 acc[4][4];
#pragma unroll
    for (int i = 0; i < 4; i++)
#pragma unroll
        for (int j = 0; j < 4; j++) acc[i][j] = (f32x4){0, 0, 0, 0};

#pragma unroll 1
    for (int k0 = 0; k0 < 512; k0 += 32) {
        __syncthreads();
        if (active) {
            gload16(Ab + (size_t)(row0 + srow) * 512 + k0 + sko, At + srow * 32 + slot);
            gload16(Ab + (size_t)(row0 + srow + 64) * 512 + k0 + sko, At + (srow + 64) * 32 + slot);
            gload16(Bb + (size_t)(col0 + srow) * 512 + k0 + sko, Bt + srow * 32 + slot);
            gload16(Bb + (size_t)(col0 + srow + 64) * 512 + k0 + sko, Bt + (srow + 64) * 32 + slot);
        }
        __syncthreads();
        if (active) {
            bf16x8 ar[4], br[4];
#pragma unroll
            for (int i = 0; i < 4; i++)
                ar[i] = *(const bf16x8*)(At + (wrow * 64 + i * 16 + l) * 32 + kc8);
#pragma unroll
            for (int j = 0; j < 4; j++)
                br[j] = *(const bf16x8*)(Bt + (wcol * 64 + j * 16 + l) * 32 + kc8);
#pragma unroll
            for (int i = 0; i < 4; i++)
#pragma unroll
                for (int j = 0; j < 4; j++)
                    acc[i][j] = __builtin_amdgcn_mfma_f32_16x16x32_bf16(ar[i], br[j], acc[i][j], 0, 0, 0);
        }
    }
    if (active) {
#pragma unroll
        for (int i = 0; i < 4; i++) {
#pragma unroll
            for (int j = 0; j < 4; j++) {
                int row = row0 + wrow * 64 + i * 16 + g * 4;
                int col = col0 + wcol * 64 + j * 16 + l;
#pragma unroll
                for (int r = 0; r < 4; r++) {
                    float bv = d.biasrow ? d.bias[row + r] : d.bias[col];
                    float o = acc[i][j][r] + bv;
                    if (d.scaleq) o *= QSCALE;
                    if (d.outf32)
                        ((float*)d.out + (size_t)z * d.sO)[(size_t)(row + r) * N + col] = o;
                    else
                        ((ushort*)d.out + (size_t)z * d.sO)[(size_t)(row + r) * N + col] = f2b(o);
                }
            }
        }
    }
}

// ---- phase 2: attention (R9 body, verbatim) ----
__device__ __forceinline__ void attn_ctx32(const ushort* __restrict__ kg,
                                           const ushort* __restrict__ vg,
                                           int M, int nt, const bf16x8 (&aq)[4],
                                           ushort* __restrict__ Kl,
                                           ushort* __restrict__ Vl,
                                           f32x16 (&o)[2], float& li,
                                           int l5, int hi, int sr, int sc, int vbase) {
    bf16x8 k0 = *(const bf16x8*)kg;
    bf16x8 k1 = *(const bf16x8*)(kg + (size_t)32 * DIM);
    bf16x8 v0 = *(const bf16x8*)vg;
    bf16x8 v1 = *(const bf16x8*)(vg + (size_t)32 * M);
    __syncthreads();
    {   // tile 0 -> buf 0
        *(bf16x8*)(Kl + sr * 72 + sc) = k0;
        *(bf16x8*)(Kl + (sr + 32) * 72 + sc) = k1;
        union { bf16x8 v; uint2 h[2]; } cv;
        cv.v = v0;
        *(uint2*)(Vl + sr * 72 + vbase) = cv.h[0];
        *(uint2*)(Vl + sr * 72 + vbase + 8) = cv.h[1];
        cv.v = v1;
        *(uint2*)(Vl + (sr + 32) * 72 + vbase) = cv.h[0];
        *(uint2*)(Vl + (sr + 32) * 72 + vbase + 8) = cv.h[1];
    }
    if (nt > 1) {
        k0 = *(const bf16x8*)(kg + (size_t)64 * DIM);
        k1 = *(const bf16x8*)(kg + (size_t)96 * DIM);
        v0 = *(const bf16x8*)(vg + 64);
        v1 = *(const bf16x8*)(vg + (size_t)32 * M + 64);
    }
    for (int i = 0; i < nt; i++) {
        __syncthreads();
        if (i + 1 < nt) {
            ushort* Kb = Kl + ((i + 1) & 1) * (64 * 72);
            ushort* Vb = Vl + ((i + 1) & 1) * (64 * 72);
            *(bf16x8*)(Kb + sr * 72 + sc) = k0;
            *(bf16x8*)(Kb + (sr + 32) * 72 + sc) = k1;
            union { bf16x8 v; uint2 h[2]; } cv;
            cv.v = v0;
            *(uint2*)(Vb + sr * 72 + vbase) = cv.h[0];
            *(uint2*)(Vb + sr * 72 + vbase + 8) = cv.h[1];
            cv.v = v1;
            *(uint2*)(Vb + (sr + 32) * 72 + vbase) = cv.h[0];
            *(uint2*)(Vb + (sr + 32) * 72 + vbase + 8) = cv.h[1];
        }
        if (i + 2 < nt) {
            size_t off = (size_t)(i + 2) * 64;
            k0 = *(const bf16x8*)(kg + off * DIM);
            k1 = *(const bf16x8*)(kg + (off + 32) * DIM);
            v0 = *(const bf16x8*)(vg + off);
            v1 = *(const bf16x8*)(vg + (size_t)32 * M + off);
        }
        const ushort* Kc = Kl + (i & 1) * (64 * 72);
        const ushort* Vc = Vl + (i & 1) * (64 * 72);
        uint2 pq[2][4];
#pragma unroll
        for (int c = 0; c < 2; c++) {
            bf16x8 kf[4];
#pragma unroll
            for (int kd = 0; kd < 4; kd++)
                kf[kd] = *(const bf16x8*)(Kc + (32 * c + l5) * 72 + kd * 16 + hi * 8);
            f32x16 s;
#pragma unroll
            for (int ii = 0; ii < 16; ii++) s[ii] = 0.f;
#pragma unroll
            for (int kd = 0; kd < 4; kd++)
                s = __builtin_amdgcn_mfma_f32_32x32x16_bf16(kf[kd], aq[kd], s, 0, 0, 0);
#pragma unroll
            for (int m = 0; m < 4; m++) {
                float p0 = fexp2(s[4 * m + 0]);
                float p1 = fexp2(s[4 * m + 1]);
                float p2 = fexp2(s[4 * m + 2]);
                float p3 = fexp2(s[4 * m + 3]);
                li += (p0 + p1) + (p2 + p3);
                pq[c][m].x = pk2bf(p0, p1);
                pq[c][m].y = pk2bf(p2, p3);
            }
        }
#pragma unroll
        for (int kc = 0; kc < 4; kc++) {
            int c = kc >> 1, m0 = 2 * (kc & 1);
            union { bf16x8 v; uint u[4]; } w;
            w.u[0] = pq[c][m0].x;     w.u[1] = pq[c][m0].y;
            w.u[2] = pq[c][m0 + 1].x; w.u[3] = pq[c][m0 + 1].y;
#pragma unroll
            for (int dn = 0; dn < 2; dn++) {
                bf16x8 vf = *(const bf16x8*)(Vc + (32 * dn + l5) * 72 + kc * 16 + hi * 8);
                o[dn] = __builtin_amdgcn_mfma_f32_32x32x16_bf16(w.v, vf, o[dn], 0, 0, 0);
            }
        }
    }
}

__device__ __forceinline__ void attn_unit(const Args& a, int u, int t, ushort* smem) {
    int grp = t >> 8;
    int tg = t & 255;
    int wg = tg >> 6;
    int ln = t & 63, l5 = ln & 31, hi = ln >> 5;
    ushort* Kl = smem + grp * 18432;
    ushort* Vl = Kl + 9216;
    float* osc = (float*)(smem + 18432);
    int qblk = u & 15, h = (u >> 4) & 7, bi = u >> 7;
    int q0 = qblk * 128 + wg * 32;
    bf16x8 aq[4];
    const ushort* qp = a.qb + (size_t)(bi * NQ + q0 + l5) * DIM + h * 64 + hi * 8;
#pragma unroll
    for (int kd = 0; kd < 4; kd++) aq[kd] = *(const bf16x8*)(qp + kd * 16);
    int sr = tg >> 3, sc = (tg & 7) * 8;
    int vbase = (sc >> 4) * 16 + ((sc >> 3) & 1) * 4;

    f32x16 o[2];
#pragma unroll
    for (int dn = 0; dn < 2; dn++)
#pragma unroll
        for (int i = 0; i < 16; i++) o[dn][i] = 0.f;
    float li = 0.f;

    attn_ctx32(a.kab + (size_t)bi * MA * DIM + (size_t)(grp * 1024 + sr) * DIM + h * 64 + sc,
               a.vta + (size_t)bi * DIM * MA + (size_t)(h * 64 + sr) * MA + grp * 1024 + sc,
               MA, 16, aq, Kl, Vl, o, li, l5, hi, sr, sc, vbase);
    li += __shfl_xor(li, 32);
    __syncthreads();
    if (grp) {
        float* p = osc + (wg * 64 + ln) * 34;
#pragma unroll
        for (int dn = 0; dn < 2; dn++)
#pragma unroll
            for (int k = 0; k < 8; k++)
                *(float2*)(p + dn * 16 + 2 * k) = (float2){o[dn][2 * k], o[dn][2 * k + 1]};
        p[32] = li;
    }
    __syncthreads();
    float yv[2][16];
    if (!grp) {
        const float* p = osc + (wg * 64 + ln) * 34;
#pragma unroll
        for (int dn = 0; dn < 2; dn++)
#pragma unroll
            for (int k = 0; k < 16; k++) o[dn][k] += p[dn * 16 + k];
        li += p[32];
        float inv[16];
#pragma unroll
        for (int rg = 0; rg < 16; rg++)
            inv[rg] = 1.f / __shfl(li, (rg & 3) + 8 * (rg >> 2) + 4 * hi);
#pragma unroll
        for (int dn = 0; dn < 2; dn++)
#pragma unroll
            for (int rg = 0; rg < 16; rg++) yv[dn][rg] = o[dn][rg] * inv[rg];
    }

#pragma unroll
    for (int dn = 0; dn < 2; dn++)
#pragma unroll
        for (int i = 0; i < 16; i++) o[dn][i] = 0.f;
    li = 0.f;
    attn_ctx32(a.ksb + (size_t)bi * MS * DIM + (size_t)(grp * 128 + sr) * DIM + h * 64 + sc,
               a.vts + (size_t)bi * DIM * MS + (size_t)(h * 64 + sr) * MS + grp * 128 + sc,
               MS, 2, aq, Kl, Vl, o, li, l5, hi, sr, sc, vbase);
    li += __shfl_xor(li, 32);
    __syncthreads();
    if (grp) {
        float* p = osc + (wg * 64 + ln) * 34;
#pragma unroll
        for (int dn = 0; dn < 2; dn++)
#pragma unroll
            for (int k = 0; k < 8; k++)
                *(float2*)(p + dn * 16 + 2 * k) = (float2){o[dn][2 * k], o[dn][2 * k + 1]};
        p[32] = li;
    }
    __syncthreads();
    if (!grp) {
        const float* p = osc + (wg * 64 + ln) * 34;
#pragma unroll
        for (int dn = 0; dn < 2; dn++)
#pragma unroll
            for (int k = 0; k < 16; k++) o[dn][k] += p[dn * 16 + k];
        li += p[32];
        float inv[16];
#pragma unroll
        for (int rg = 0; rg < 16; rg++)
            inv[rg] = 1.f / __shfl(li, (rg & 3) + 8 * (rg >> 2) + 4 * hi);
#pragma unroll
        for (int dn = 0; dn < 2; dn++)
#pragma unroll
            for (int rg = 0; rg < 16; rg++) {
                int qr = (rg & 3) + 8 * (rg >> 2) + 4 * hi;
                float ov = yv[dn][rg] + o[dn][rg] * inv[rg];
                a.yb[(size_t)(bi * NQ + q0 + qr) * DIM + h * 64 + 32 * dn + l5] = f2b(ov);
            }
    }
}

// ---- phase 3: projection, 8-wave 128x128 tile (all 512 threads) ----
__device__ __forceinline__ void proj_unit(const Args& a, int u, int t,
                                          ushort* At, ushort* Bt) {
    int x = u & 63, y = u >> 6;
    int wv = t >> 6, ln = t & 63, l = ln & 15, g = ln >> 4;
    int wrow = wv & 1, wcol = wv >> 1;   // 2 x 4 wave grid
    int row0 = x * 128, col0 = y * 128;
    int srow = t >> 2;                   // 0..127
    int slot = (t & 3) * 8;
    int sko = ((t ^ srow) & 3) * 8;
    int kc8 = ((g ^ (l & 3)) & 3) * 8;

    f32x4 acc[4][2];
#pragma unroll
    for (int i = 0; i < 4; i++)
#pragma unroll
        for (int j = 0; j < 2; j++) acc[i][j] = (f32x4){0, 0, 0, 0};

#pragma unroll 1
    for (int k0 = 0; k0 < 512; k0 += 32) {
        __syncthreads();
        gload16(a.pa + (size_t)(row0 + srow) * 512 + k0 + sko, At + srow * 32 + slot);
        gload16(a.pw + (size_t)(col0 + srow) * 512 + k0 + sko, Bt + srow * 32 + slot);
        __syncthreads();
        bf16x8 ar[4], br[2];
#pragma unroll
        for (int i = 0; i < 4; i++)
            ar[i] = *(const bf16x8*)(At + (wrow * 64 + i * 16 + l) * 32 + kc8);
#pragma unroll
        for (int j = 0; j < 2; j++)
            br[j] = *(const bf16x8*)(Bt + (wcol * 32 + j * 16 + l) * 32 + kc8);
#pragma unroll
        for (int i = 0; i < 4; i++)
#pragma unroll
            for (int j = 0; j < 2; j++)
                acc[i][j] = __builtin_amdgcn_mfma_f32_16x16x32_bf16(ar[i], br[j], acc[i][j], 0, 0, 0);
    }
#pragma unroll
    for (int i = 0; i < 4; i++) {
#pragma unroll
        for (int j = 0; j < 2; j++) {
            int row = row0 + wrow * 64 + i * 16 + g * 4;
            int col = col0 + wcol * 32 + j * 16 + l;
#pragma unroll
            for (int r = 0; r < 4; r++)
                a.pout[(size_t)(row + r) * 512 + col] = acc[i][j][r] + a.pbias[col];
        }
    }
}

__global__ __launch_bounds__(512, 2) void mega(Args a) {
    __shared__ ushort smem[36864];  // 73728 B: attn layout; gemm/proj reuse prefix
    int b = blockIdx.x, t = threadIdx.x;

    cast_phase(a, b, t);
    gsync(a.bar, 256);

    {   // QKV: 832 units = 2 rounds x (256 blocks x 2 halves)
        int hh = t >> 8, t2 = t & 255;
        ushort* At = smem + hh * 8192;
        ushort* Bt = At + 4096;
#pragma unroll 1
        for (int r = 0; r < 2; r++) {
            int u = r * 512 + b * 2 + hh;
            bool act = u < 832;
            gemm_qkv(a, act ? u : 0, t2, At, Bt, act);
        }
    }
    gsync(a.bar, 512);

#pragma unroll 1
    for (int r = 0; r < 2; r++)
        attn_unit(a, b + r * 256, t, smem);
    gsync(a.bar, 768);

    proj_unit(a, b, t, smem, smem + 4096);
}

extern "C" void kernel_launch(void* const* d_in, const int* in_sizes, int n_in,
                              void* d_out, int out_size, void* d_ws, size_t ws_size,
                              hipStream_t stream) {
    const float* x   = (const float*)d_in[0];
    const float* ac  = (const float*)d_in[1];
    const float* scx = (const float*)d_in[2];
    const float* Wq  = (const float*)d_in[3];
    const float* bq  = (const float*)d_in[4];
    const float* Wka = (const float*)d_in[5];
    const float* bka = (const float*)d_in[6];
    const float* Wva = (const float*)d_in[7];
    const float* bva = (const float*)d_in[8];
    const float* Wks = (const float*)d_in[9];
    const float* bks = (const float*)d_in[10];
    const float* Wvs = (const float*)d_in[11];
    const float* bvs = (const float*)d_in[12];
    const float* Wp  = (const float*)d_in[13];
    const float* bp  = (const float*)d_in[14];

    ushort* wb   = (ushort*)d_ws;         // contiguous cast dst (R12 layout):
    ushort* wqb  = wb;                    // [6 weights][xb][acb][scxb]
    ushort* wkab = wb + 262144;
    ushort* wvab = wb + 2 * 262144;
    ushort* wksb = wb + 3 * 262144;
    ushort* wvsb = wb + 4 * 262144;
    ushort* wpb  = wb + 5 * 262144;
    ushort* xb   = wb + 6 * 262144;       // [8192][512]
    ushort* acb  = xb + 4194304;          // [8192][512]
    ushort* scxb = acb + 4194304;         // [1024][512]
    ushort* qb   = scxb + 524288;         // [8192][512] prescaled q
    ushort* kab  = qb + 4194304;          // [8192][512]
    ushort* vta  = kab + 4194304;         // [4][512][2048] V^T
    ushort* ksb  = vta + 4194304;         // [1024][512]
    ushort* vts  = ksb + 524288;          // [4][512][256]  V^T
    ushort* yb   = xb;                    // alias: x dead after gemm phase

    uint* bar = (uint*)((char*)d_out + out_size - 64);
    hipMemsetAsync(bar, 0, 64, stream);   // barrier counter; proj overwrites post-sync

    Args a;
    a.w0 = Wq; a.w1 = Wka; a.w2 = Wva; a.w3 = Wks; a.w4 = Wvs; a.w5 = Wp;
    a.xs = x; a.acs = ac; a.scxs = scx; a.wb = wb;
    a.g0 = (GD){xb,   wqb,  bq,  qb,  0, 0,                    512,  64, 4,  0,   0, 1, 0, 0};
    a.g1 = (GD){acb,  wkab, bka, kab, 0, 0,                    512,  64, 4,  256, 0, 0, 0, 0};
    a.g2 = (GD){wvab, acb,  bva, vta, 2048L * 512, 512L * 2048, 2048, 4, 16, 512, 1, 0, 0, 0};
    a.g3 = (GD){scxb, wksb, bks, ksb, 0, 0,                    512,  8,  4,  768, 0, 0, 0, 0};
    a.g4 = (GD){wvsb, scxb, bvs, vts, 256L * 512, 512L * 256,   256,  4,  2,  800, 1, 0, 0, 0};
    a.qb = qb; a.kab = kab; a.vta = vta; a.ksb = ksb; a.vts = vts; a.yb = yb;
    a.pa = yb; a.pw = wpb; a.pbias = bp; a.pout = (float*)d_out;
    a.bar = bar;

    mega<<<256, 512, 0, stream>>>(a);
}

// Round 9
// 373.473 us; speedup vs baseline: 1.0399x; 1.0399x over previous
//
#include <hip/hip_runtime.h>

// R16: fix R15's replay race. R15's 64q attn was numerically correct (initial
// absmax passed) but diverged on graph replay: its 66-float exchange slots
// spanned the WHOLE smem, aliasing grp0's live K/V double-buffer. R12's
// proven discipline: exchange lives strictly in grp1's dead staging half.
// Restore that by splitting the exchange into TWO sequential 34-float rounds
// (one per q-half), each fitting grp1's region (256x34x4 = 34816B <= 36864B).
// +2 barriers/phase, everything else R15-identical: 64 q-rows/wave halves
// the K/V stream (256 blocks, stride-72 reg-staged LDS, 16K conflicts),
// cast_all + single-buffer R4 gemm (54.6us) + proj unchanged.
#define DIM 512
#define NQ 2048
#define MA 2048
#define MS 256
#define QSCALE 0.06375864651f  // 512^-0.5 * log2(e)

typedef __attribute__((ext_vector_type(8))) short bf16x8;
typedef __attribute__((ext_vector_type(4))) float f32x4;
typedef __attribute__((ext_vector_type(16))) float f32x16;

__device__ __forceinline__ ushort f2b(float f) {
    uint u = __float_as_uint(f);
    u = (u + 0x7fffu + ((u >> 16) & 1u)) >> 16;
    return (ushort)u;
}

__device__ __forceinline__ uint pk2bf(float a, float b) {
#if __has_builtin(__builtin_amdgcn_cvt_pk_bf16_f32)
    typedef __attribute__((ext_vector_type(2))) __bf16 bf2;
    bf2 r = __builtin_amdgcn_cvt_pk_bf16_f32(a, b);
    uint u;
    __builtin_memcpy(&u, &r, 4);
    return u;
#else
    return ((__float_as_uint(a) + 0x8000u) >> 16) |
           ((__float_as_uint(b) + 0x8000u) & 0xffff0000u);
#endif
}

__device__ __forceinline__ float fexp2(float x) {
#if __has_builtin(__builtin_amdgcn_exp2f)
    return __builtin_amdgcn_exp2f(x);
#else
    return exp2f(x);
#endif
}

__device__ __forceinline__ void gload16(const ushort* g, ushort* l) {
    __builtin_amdgcn_global_load_lds(
        (const __attribute__((address_space(1))) void*)g,
        (__attribute__((address_space(3))) void*)l, 16, 0, 0);
}

// ---- fused cast: 6 weights + x + ac + scx -> contiguous bf16 region ----
__global__ __launch_bounds__(256) void cast_all(const float* __restrict__ w0,
                                                const float* __restrict__ w1,
                                                const float* __restrict__ w2,
                                                const float* __restrict__ w3,
                                                const float* __restrict__ w4,
                                                const float* __restrict__ w5,
                                                const float* __restrict__ x,
                                                const float* __restrict__ ac,
                                                const float* __restrict__ scx,
                                                ushort* __restrict__ dst) {
    int i = blockIdx.x * 256 + threadIdx.x;  // float4 index, 2621440 total
    const float* s;
    int o;
    if (i < 393216) {
        int w = i >> 16;
        s = w < 3 ? (w == 0 ? w0 : (w == 1 ? w1 : w2))
                  : (w == 3 ? w3 : (w == 4 ? w4 : w5));
        o = i & 65535;
    } else if (i < 1441792) { s = x;   o = i - 393216; }
    else if (i < 2490368)   { s = ac;  o = i - 1441792; }
    else                    { s = scx; o = i - 2490368; }
    float4 v = ((const float4*)s)[o];
    ushort4 u;
    u.x = f2b(v.x); u.y = f2b(v.y); u.z = f2b(v.z); u.w = f2b(v.w);
    ((ushort4*)dst)[i] = u;
}

// ---- fused GEMM (R4 single-buffer, measured 54.6us): C = A@B^T + bias ----
struct GD {
    const ushort* A; const ushort* B; const float* bias; void* out;
    long sB, sO;
    int N, bx, by, blk0, biasrow, scaleq, outf32, pad;
};

__global__ __launch_bounds__(256) void gemm_fused(GD d0, GD d1, GD d2, GD d3, GD d4) {
    __shared__ ushort At[128 * 32];
    __shared__ ushort Bt[128 * 32];
    GD d = d0;
    int bid = blockIdx.x;
    if (bid >= d1.blk0) d = d1;
    if (bid >= d2.blk0) d = d2;
    if (bid >= d3.blk0) d = d3;
    if (bid >= d4.blk0) d = d4;
    int local = bid - d.blk0;
    int x = local % d.bx;
    int rem = local / d.bx;
    int y = rem % d.by;
    int z = rem / d.by;

    int t = threadIdx.x;
    int wv = t >> 6, ln = t & 63, l = ln & 15, g = ln >> 4;
    int wrow = wv & 1, wcol = wv >> 1;
    int row0 = x * 128, col0 = y * 128;
    int srow = t >> 2;
    int slot = (t & 3) * 8;
    int sko = ((t ^ srow) & 3) * 8;        // XOR-swizzled global k-chunk
    int kc8 = ((g ^ (l & 3)) & 3) * 8;     // reader un-swizzle
    const ushort* Ab = d.A;
    const ushort* Bb = d.B + (size_t)z * d.sB;
    int N = d.N;

    f32x4 acc[4][4];
#pragma unroll
    for (int i = 0; i < 4; i++)
#pragma unroll
        for (int j = 0; j < 4; j++) acc[i][j] = (f32x4){0, 0, 0, 0};

    for (int k0 = 0; k0 < 512; k0 += 32) {
        __syncthreads();
#pragma unroll
        for (int c = 0; c < 2; c++) {
            gload16(Ab + (size_t)(row0 + srow + 64 * c) * 512 + k0 + sko,
                    At + (srow + 64 * c) * 32 + slot);
            gload16(Bb + (size_t)(col0 + srow + 64 * c) * 512 + k0 + sko,
                    Bt + (srow + 64 * c) * 32 + slot);
        }
        __syncthreads();
        bf16x8 ar[4], br[4];
#pragma unroll
        for (int i = 0; i < 4; i++)
            ar[i] = *(const bf16x8*)(At + (wrow * 64 + i * 16 + l) * 32 + kc8);
#pragma unroll
        for (int j = 0; j < 4; j++)
            br[j] = *(const bf16x8*)(Bt + (wcol * 64 + j * 16 + l) * 32 + kc8);
#pragma unroll
        for (int i = 0; i < 4; i++)
#pragma unroll
            for (int j = 0; j < 4; j++)
                acc[i][j] = __builtin_amdgcn_mfma_f32_16x16x32_bf16(ar[i], br[j], acc[i][j], 0, 0, 0);
    }
#pragma unroll
    for (int i = 0; i < 4; i++) {
#pragma unroll
        for (int j = 0; j < 4; j++) {
            int row = row0 + wrow * 64 + i * 16 + g * 4;
            int col = col0 + wcol * 64 + j * 16 + l;
#pragma unroll
            for (int r = 0; r < 4; r++) {
                float bv = d.biasrow ? d.bias[row + r] : d.bias[col];
                float o = acc[i][j][r] + bv;
                if (d.scaleq) o *= QSCALE;
                if (d.outf32)
                    ((float*)d.out + (size_t)z * d.sO)[(size_t)(row + r) * N + col] = o;
                else
                    ((ushort*)d.out + (size_t)z * d.sO)[(size_t)(row + r) * N + col] = f2b(o);
            }
        }
    }
}

// ---- attention inner loop: 64 q-rows/wave, R9 staging/layout verbatim ----
// Stride-72 LDS K/V dbuf, reg-staged, 1 barrier/tile. V-frag reads shared by
// both q-halves (the 2x traffic win). PV folded per-c: pq[2][4] only.
__device__ __forceinline__ void attn_ctx64(const ushort* __restrict__ kg,
                                           const ushort* __restrict__ vg,
                                           int M, int nt, const bf16x8 (&aq)[2][4],
                                           ushort* __restrict__ Kl,
                                           ushort* __restrict__ Vl,
                                           f32x16 (&o)[4], float (&li)[2],
                                           int l5, int hi, int sr, int sc, int vbase) {
    bf16x8 k0 = *(const bf16x8*)kg;
    bf16x8 k1 = *(const bf16x8*)(kg + (size_t)32 * DIM);
    bf16x8 v0 = *(const bf16x8*)vg;
    bf16x8 v1 = *(const bf16x8*)(vg + (size_t)32 * M);
    __syncthreads();
    {   // tile 0 -> buf 0
        *(bf16x8*)(Kl + sr * 72 + sc) = k0;
        *(bf16x8*)(Kl + (sr + 32) * 72 + sc) = k1;
        union { bf16x8 v; uint2 h[2]; } cv;
        cv.v = v0;
        *(uint2*)(Vl + sr * 72 + vbase) = cv.h[0];
        *(uint2*)(Vl + sr * 72 + vbase + 8) = cv.h[1];
        cv.v = v1;
        *(uint2*)(Vl + (sr + 32) * 72 + vbase) = cv.h[0];
        *(uint2*)(Vl + (sr + 32) * 72 + vbase + 8) = cv.h[1];
    }
    if (nt > 1) {
        k0 = *(const bf16x8*)(kg + (size_t)64 * DIM);
        k1 = *(const bf16x8*)(kg + (size_t)96 * DIM);
        v0 = *(const bf16x8*)(vg + 64);
        v1 = *(const bf16x8*)(vg + (size_t)32 * M + 64);
    }
    for (int i = 0; i < nt; i++) {
        __syncthreads();
        if (i + 1 < nt) {
            ushort* Kb = Kl + ((i + 1) & 1) * (64 * 72);
            ushort* Vb = Vl + ((i + 1) & 1) * (64 * 72);
            *(bf16x8*)(Kb + sr * 72 + sc) = k0;
            *(bf16x8*)(Kb + (sr + 32) * 72 + sc) = k1;
            union { bf16x8 v; uint2 h[2]; } cv;
            cv.v = v0;
            *(uint2*)(Vb + sr * 72 + vbase) = cv.h[0];
            *(uint2*)(Vb + sr * 72 + vbase + 8) = cv.h[1];
            cv.v = v1;
            *(uint2*)(Vb + (sr + 32) * 72 + vbase) = cv.h[0];
            *(uint2*)(Vb + (sr + 32) * 72 + vbase + 8) = cv.h[1];
        }
        if (i + 2 < nt) {
            size_t off = (size_t)(i + 2) * 64;
            k0 = *(const bf16x8*)(kg + off * DIM);
            k1 = *(const bf16x8*)(kg + (off + 32) * DIM);
            v0 = *(const bf16x8*)(vg + off);
            v1 = *(const bf16x8*)(vg + (size_t)32 * M + off);
        }
        const ushort* Kc = Kl + (i & 1) * (64 * 72);
        const ushort* Vc = Vl + (i & 1) * (64 * 72);
#pragma unroll
        for (int c = 0; c < 2; c++) {
            bf16x8 kf[4];
#pragma unroll
            for (int kd = 0; kd < 4; kd++)
                kf[kd] = *(const bf16x8*)(Kc + (32 * c + l5) * 72 + kd * 16 + hi * 8);
            uint2 pq[2][4];
#pragma unroll
            for (int qh = 0; qh < 2; qh++) {
                f32x16 s;
#pragma unroll
                for (int ii = 0; ii < 16; ii++) s[ii] = 0.f;
#pragma unroll
                for (int kd = 0; kd < 4; kd++)
                    s = __builtin_amdgcn_mfma_f32_32x32x16_bf16(kf[kd], aq[qh][kd], s, 0, 0, 0);
#pragma unroll
                for (int m = 0; m < 4; m++) {
                    float p0 = fexp2(s[4 * m + 0]);
                    float p1 = fexp2(s[4 * m + 1]);
                    float p2 = fexp2(s[4 * m + 2]);
                    float p3 = fexp2(s[4 * m + 3]);
                    li[qh] += (p0 + p1) + (p2 + p3);
                    pq[qh][m].x = pk2bf(p0, p1);
                    pq[qh][m].y = pk2bf(p2, p3);
                }
            }
            // PV for this c's two k-slots; vf shared across both q-halves
#pragma unroll
            for (int kk = 0; kk < 2; kk++) {
                int kc = 2 * c + kk, m0 = 2 * kk;
                bf16x8 vf0 = *(const bf16x8*)(Vc + l5 * 72 + kc * 16 + hi * 8);
                bf16x8 vf1 = *(const bf16x8*)(Vc + (32 + l5) * 72 + kc * 16 + hi * 8);
#pragma unroll
                for (int qh = 0; qh < 2; qh++) {
                    union { bf16x8 v; uint u[4]; } w;
                    w.u[0] = pq[qh][m0].x;     w.u[1] = pq[qh][m0].y;
                    w.u[2] = pq[qh][m0 + 1].x; w.u[3] = pq[qh][m0 + 1].y;
                    o[qh * 2 + 0] = __builtin_amdgcn_mfma_f32_32x32x16_bf16(w.v, vf0, o[qh * 2 + 0], 0, 0, 0);
                    o[qh * 2 + 1] = __builtin_amdgcn_mfma_f32_32x32x16_bf16(w.v, vf1, o[qh * 2 + 1], 0, 0, 0);
                }
            }
        }
    }
}

// 512 threads: grp = ctx half, wave wg (0..3) owns 64 q-rows; block = 256 q.
// Exchange: TWO sequential rounds (one per q-half) of 34-float slots living
// strictly in grp1's dead staging region (R12-proven aliasing discipline;
// grp0's staging region is never aliased by exchange traffic).
__global__ __launch_bounds__(512) void attn_kernel(const ushort* __restrict__ q,
                                                   const ushort* __restrict__ Ka,
                                                   const ushort* __restrict__ VTa,
                                                   const ushort* __restrict__ Ks,
                                                   const ushort* __restrict__ VTs,
                                                   ushort* __restrict__ y) {
    __shared__ ushort smem[2 * 18432];  // [grp][Kl 9216 | Vl 9216]
    int t = threadIdx.x;
    int grp = t >> 8;
    int tg = t & 255;
    int wg = tg >> 6;
    int ln = t & 63, l5 = ln & 31, hi = ln >> 5;
    ushort* Kl = smem + grp * 18432;
    ushort* Vl = Kl + 9216;
    float* osc = (float*)(smem + 18432);  // grp1 region ONLY: 256*34*4 B fits
    int h = blockIdx.y, bi = blockIdx.z;
    int q0 = blockIdx.x * 256 + wg * 64;
    bf16x8 aq[2][4];
#pragma unroll
    for (int qh = 0; qh < 2; qh++) {
        const ushort* qp = q + (size_t)(bi * NQ + q0 + qh * 32 + l5) * DIM + h * 64 + hi * 8;
#pragma unroll
        for (int kd = 0; kd < 4; kd++) aq[qh][kd] = *(const bf16x8*)(qp + kd * 16);
    }
    int sr = tg >> 3, sc = (tg & 7) * 8;
    int vbase = (sc >> 4) * 16 + ((sc >> 3) & 1) * 4;  // permuted V slot base

    f32x16 o[4];
#pragma unroll
    for (int k = 0; k < 4; k++)
#pragma unroll
        for (int i = 0; i < 16; i++) o[k][i] = 0.f;
    float li[2] = {0.f, 0.f};

    // audio (long) first: group grp handles ctx [grp*1024, grp*1024+1024)
    attn_ctx64(Ka + (size_t)bi * MA * DIM + (size_t)(grp * 1024 + sr) * DIM + h * 64 + sc,
               VTa + (size_t)bi * DIM * MA + (size_t)(h * 64 + sr) * MA + grp * 1024 + sc,
               MA, 16, aq, Kl, Vl, o, li, l5, hi, sr, sc, vbase);
    li[0] += __shfl_xor(li[0], 32);
    li[1] += __shfl_xor(li[1], 32);
    float yv[4][16];
    float* p = osc + tg * 34;
#pragma unroll 1
    for (int qh = 0; qh < 2; qh++) {
        __syncthreads();  // qh=0: staging reads done; qh=1: round-0 reads done
        if (grp) {
#pragma unroll
            for (int dn = 0; dn < 2; dn++)
#pragma unroll
                for (int r = 0; r < 8; r++)
                    *(float2*)(p + dn * 16 + 2 * r) =
                        (float2){o[qh * 2 + dn][2 * r], o[qh * 2 + dn][2 * r + 1]};
            p[32] = li[qh];
        }
        __syncthreads();  // partials visible
        if (!grp) {
#pragma unroll
            for (int dn = 0; dn < 2; dn++)
#pragma unroll
                for (int r = 0; r < 16; r++) o[qh * 2 + dn][r] += p[dn * 16 + r];
            li[qh] += p[32];
            float inv[16];
#pragma unroll
            for (int rg = 0; rg < 16; rg++)
                inv[rg] = 1.f / __shfl(li[qh], (rg & 3) + 8 * (rg >> 2) + 4 * hi);
#pragma unroll
            for (int dn = 0; dn < 2; dn++)
#pragma unroll
                for (int rg = 0; rg < 16; rg++)
                    yv[qh * 2 + dn][rg] = o[qh * 2 + dn][rg] * inv[rg];
        }
    }

#pragma unroll
    for (int k = 0; k < 4; k++)
#pragma unroll
        for (int i = 0; i < 16; i++) o[k][i] = 0.f;
    li[0] = li[1] = 0.f;
    // singer (short): group grp handles ctx [grp*128, grp*128+128)
    attn_ctx64(Ks + (size_t)bi * MS * DIM + (size_t)(grp * 128 + sr) * DIM + h * 64 + sc,
               VTs + (size_t)bi * DIM * MS + (size_t)(h * 64 + sr) * MS + grp * 128 + sc,
               MS, 2, aq, Kl, Vl, o, li, l5, hi, sr, sc, vbase);
    li[0] += __shfl_xor(li[0], 32);
    li[1] += __shfl_xor(li[1], 32);
#pragma unroll 1
    for (int qh = 0; qh < 2; qh++) {
        __syncthreads();  // qh=0: singer staging reads done; qh=1: round-0 done
        if (grp) {
#pragma unroll
            for (int dn = 0; dn < 2; dn++)
#pragma unroll
                for (int r = 0; r < 8; r++)
                    *(float2*)(p + dn * 16 + 2 * r) =
                        (float2){o[qh * 2 + dn][2 * r], o[qh * 2 + dn][2 * r + 1]};
            p[32] = li[qh];
        }
        __syncthreads();
        if (!grp) {
#pragma unroll
            for (int dn = 0; dn < 2; dn++)
#pragma unroll
                for (int r = 0; r < 16; r++) o[qh * 2 + dn][r] += p[dn * 16 + r];
            li[qh] += p[32];
            float inv[16];
#pragma unroll
            for (int rg = 0; rg < 16; rg++)
                inv[rg] = 1.f / __shfl(li[qh], (rg & 3) + 8 * (rg >> 2) + 4 * hi);
            // O: lane holds d = 32*dn + l5, q = q0 + qh*32 + crow(rg,hi)
#pragma unroll
            for (int dn = 0; dn < 2; dn++)
#pragma unroll
                for (int rg = 0; rg < 16; rg++) {
                    int qr = (rg & 3) + 8 * (rg >> 2) + 4 * hi;
                    float ov = yv[qh * 2 + dn][rg] + o[qh * 2 + dn][rg] * inv[rg];
                    y[(size_t)(bi * NQ + q0 + qh * 32 + qr) * DIM + h * 64 + 32 * dn + l5] = f2b(ov);
                }
        }
    }
}

extern "C" void kernel_launch(void* const* d_in, const int* in_sizes, int n_in,
                              void* d_out, int out_size, void* d_ws, size_t ws_size,
                              hipStream_t stream) {
    const float* x   = (const float*)d_in[0];
    const float* ac  = (const float*)d_in[1];
    const float* scx = (const float*)d_in[2];
    const float* Wq  = (const float*)d_in[3];
    const float* bq  = (const float*)d_in[4];
    const float* Wka = (const float*)d_in[5];
    const float* bka = (const float*)d_in[6];
    const float* Wva = (const float*)d_in[7];
    const float* bva = (const float*)d_in[8];
    const float* Wks = (const float*)d_in[9];
    const float* bks = (const float*)d_in[10];
    const float* Wvs = (const float*)d_in[11];
    const float* bvs = (const float*)d_in[12];
    const float* Wp  = (const float*)d_in[13];
    const float* bp  = (const float*)d_in[14];

    ushort* wb   = (ushort*)d_ws;         // contiguous cast dst:
    ushort* wqb  = wb;                    // [6 weights][xb][acb][scxb]
    ushort* wkab = wb + 262144;
    ushort* wvab = wb + 2 * 262144;
    ushort* wksb = wb + 3 * 262144;
    ushort* wvsb = wb + 4 * 262144;
    ushort* wpb  = wb + 5 * 262144;
    ushort* xb   = wb + 6 * 262144;       // [8192][512]
    ushort* acb  = xb + 4194304;          // [8192][512]
    ushort* scxb = acb + 4194304;         // [1024][512]
    ushort* qb   = scxb + 524288;         // [8192][512] prescaled q
    ushort* kab  = qb + 4194304;          // [8192][512]
    ushort* vta  = kab + 4194304;         // [4][512][2048] V^T
    ushort* ksb  = vta + 4194304;         // [1024][512]
    ushort* vts  = ksb + 524288;          // [4][512][256]  V^T
    ushort* yb   = xb;                    // alias: x dead after gemm_fused

    cast_all<<<10240, 256, 0, stream>>>(Wq, Wka, Wva, Wks, Wvs, Wp, x, ac, scx, wb);

    GD gq   = {xb,   wqb,  bq,  qb,  0, 0,               512,  64, 4,  0,   0, 1, 0, 0};
    GD gka  = {acb,  wkab, bka, kab, 0, 0,               512,  64, 4,  256, 0, 0, 0, 0};
    GD gvta = {wvab, acb,  bva, vta, 2048L * 512, 512L * 2048, 2048, 4, 16, 512, 1, 0, 0, 0};
    GD gks  = {scxb, wksb, bks, ksb, 0, 0,               512,  8,  4,  768, 0, 0, 0, 0};
    GD gvts = {wvsb, scxb, bvs, vts, 256L * 512, 512L * 256,   256,  4,  2,  800, 1, 0, 0, 0};
    gemm_fused<<<832, 256, 0, stream>>>(gq, gka, gvta, gks, gvts);

    attn_kernel<<<dim3(8, 8, 4), 512, 0, stream>>>(qb, kab, vta, ksb, vts, yb);

    GD gpr = {yb, wpb, bp, d_out, 0, 0, 512, 64, 4, 0, 0, 0, 1, 0};
    GD gnv = {nullptr, nullptr, nullptr, nullptr, 0, 0, 0, 1, 1, 1 << 30, 0, 0, 0, 0};
    gemm_fused<<<256, 256, 0, stream>>>(gpr, gnv, gnv, gnv, gnv);
}

// Round 10
// 229.855 us; speedup vs baseline: 1.6897x; 1.6248x over previous
//
#include <hip/hip_runtime.h>

// R17: fix R16's rule-#20 scratch demotion. R16 sequenced the two exchange
// rounds with `#pragma unroll 1 for(qh)` -> runtime qh indexes o[qh*2+dn] /
// yv[qh*2+dn] -> whole accumulator state demoted to scratch (WRITE_SIZE
// 710MB, FETCH 310MB, attn 229us at VGPR=124). Fix: FULL unroll of the qh
// exchange loops -- static indices, registers restored; emitted barrier
// sequence is identical (program order), so R16's race fix (exchange
// confined to grp1's dead staging half, two 34-float rounds) is preserved.
// Everything else byte-identical to R16: 64q/wave attn (halved K/V stream),
// stride-72 reg-staged LDS, cast_all + R4 single-buffer gemm + proj.
#define DIM 512
#define NQ 2048
#define MA 2048
#define MS 256
#define QSCALE 0.06375864651f  // 512^-0.5 * log2(e)

typedef __attribute__((ext_vector_type(8))) short bf16x8;
typedef __attribute__((ext_vector_type(4))) float f32x4;
typedef __attribute__((ext_vector_type(16))) float f32x16;

__device__ __forceinline__ ushort f2b(float f) {
    uint u = __float_as_uint(f);
    u = (u + 0x7fffu + ((u >> 16) & 1u)) >> 16;
    return (ushort)u;
}

__device__ __forceinline__ uint pk2bf(float a, float b) {
#if __has_builtin(__builtin_amdgcn_cvt_pk_bf16_f32)
    typedef __attribute__((ext_vector_type(2))) __bf16 bf2;
    bf2 r = __builtin_amdgcn_cvt_pk_bf16_f32(a, b);
    uint u;
    __builtin_memcpy(&u, &r, 4);
    return u;
#else
    return ((__float_as_uint(a) + 0x8000u) >> 16) |
           ((__float_as_uint(b) + 0x8000u) & 0xffff0000u);
#endif
}

__device__ __forceinline__ float fexp2(float x) {
#if __has_builtin(__builtin_amdgcn_exp2f)
    return __builtin_amdgcn_exp2f(x);
#else
    return exp2f(x);
#endif
}

__device__ __forceinline__ void gload16(const ushort* g, ushort* l) {
    __builtin_amdgcn_global_load_lds(
        (const __attribute__((address_space(1))) void*)g,
        (__attribute__((address_space(3))) void*)l, 16, 0, 0);
}

// ---- fused cast: 6 weights + x + ac + scx -> contiguous bf16 region ----
__global__ __launch_bounds__(256) void cast_all(const float* __restrict__ w0,
                                                const float* __restrict__ w1,
                                                const float* __restrict__ w2,
                                                const float* __restrict__ w3,
                                                const float* __restrict__ w4,
                                                const float* __restrict__ w5,
                                                const float* __restrict__ x,
                                                const float* __restrict__ ac,
                                                const float* __restrict__ scx,
                                                ushort* __restrict__ dst) {
    int i = blockIdx.x * 256 + threadIdx.x;  // float4 index, 2621440 total
    const float* s;
    int o;
    if (i < 393216) {
        int w = i >> 16;
        s = w < 3 ? (w == 0 ? w0 : (w == 1 ? w1 : w2))
                  : (w == 3 ? w3 : (w == 4 ? w4 : w5));
        o = i & 65535;
    } else if (i < 1441792) { s = x;   o = i - 393216; }
    else if (i < 2490368)   { s = ac;  o = i - 1441792; }
    else                    { s = scx; o = i - 2490368; }
    float4 v = ((const float4*)s)[o];
    ushort4 u;
    u.x = f2b(v.x); u.y = f2b(v.y); u.z = f2b(v.z); u.w = f2b(v.w);
    ((ushort4*)dst)[i] = u;
}

// ---- fused GEMM (R4 single-buffer, measured 54.6us): C = A@B^T + bias ----
struct GD {
    const ushort* A; const ushort* B; const float* bias; void* out;
    long sB, sO;
    int N, bx, by, blk0, biasrow, scaleq, outf32, pad;
};

__global__ __launch_bounds__(256) void gemm_fused(GD d0, GD d1, GD d2, GD d3, GD d4) {
    __shared__ ushort At[128 * 32];
    __shared__ ushort Bt[128 * 32];
    GD d = d0;
    int bid = blockIdx.x;
    if (bid >= d1.blk0) d = d1;
    if (bid >= d2.blk0) d = d2;
    if (bid >= d3.blk0) d = d3;
    if (bid >= d4.blk0) d = d4;
    int local = bid - d.blk0;
    int x = local % d.bx;
    int rem = local / d.bx;
    int y = rem % d.by;
    int z = rem / d.by;

    int t = threadIdx.x;
    int wv = t >> 6, ln = t & 63, l = ln & 15, g = ln >> 4;
    int wrow = wv & 1, wcol = wv >> 1;
    int row0 = x * 128, col0 = y * 128;
    int srow = t >> 2;
    int slot = (t & 3) * 8;
    int sko = ((t ^ srow) & 3) * 8;        // XOR-swizzled global k-chunk
    int kc8 = ((g ^ (l & 3)) & 3) * 8;     // reader un-swizzle
    const ushort* Ab = d.A;
    const ushort* Bb = d.B + (size_t)z * d.sB;
    int N = d.N;

    f32x4 acc[4][4];
#pragma unroll
    for (int i = 0; i < 4; i++)
#pragma unroll
        for (int j = 0; j < 4; j++) acc[i][j] = (f32x4){0, 0, 0, 0};

    for (int k0 = 0; k0 < 512; k0 += 32) {
        __syncthreads();
#pragma unroll
        for (int c = 0; c < 2; c++) {
            gload16(Ab + (size_t)(row0 + srow + 64 * c) * 512 + k0 + sko,
                    At + (srow + 64 * c) * 32 + slot);
            gload16(Bb + (size_t)(col0 + srow + 64 * c) * 512 + k0 + sko,
                    Bt + (srow + 64 * c) * 32 + slot);
        }
        __syncthreads();
        bf16x8 ar[4], br[4];
#pragma unroll
        for (int i = 0; i < 4; i++)
            ar[i] = *(const bf16x8*)(At + (wrow * 64 + i * 16 + l) * 32 + kc8);
#pragma unroll
        for (int j = 0; j < 4; j++)
            br[j] = *(const bf16x8*)(Bt + (wcol * 64 + j * 16 + l) * 32 + kc8);
#pragma unroll
        for (int i = 0; i < 4; i++)
#pragma unroll
            for (int j = 0; j < 4; j++)
                acc[i][j] = __builtin_amdgcn_mfma_f32_16x16x32_bf16(ar[i], br[j], acc[i][j], 0, 0, 0);
    }
#pragma unroll
    for (int i = 0; i < 4; i++) {
#pragma unroll
        for (int j = 0; j < 4; j++) {
            int row = row0 + wrow * 64 + i * 16 + g * 4;
            int col = col0 + wcol * 64 + j * 16 + l;
#pragma unroll
            for (int r = 0; r < 4; r++) {
                float bv = d.biasrow ? d.bias[row + r] : d.bias[col];
                float o = acc[i][j][r] + bv;
                if (d.scaleq) o *= QSCALE;
                if (d.outf32)
                    ((float*)d.out + (size_t)z * d.sO)[(size_t)(row + r) * N + col] = o;
                else
                    ((ushort*)d.out + (size_t)z * d.sO)[(size_t)(row + r) * N + col] = f2b(o);
            }
        }
    }
}

// ---- attention inner loop: 64 q-rows/wave, R9 staging/layout verbatim ----
// Stride-72 LDS K/V dbuf, reg-staged, 1 barrier/tile. V-frag reads shared by
// both q-halves (the 2x traffic win). PV folded per-c: pq[2][4] only.
__device__ __forceinline__ void attn_ctx64(const ushort* __restrict__ kg,
                                           const ushort* __restrict__ vg,
                                           int M, int nt, const bf16x8 (&aq)[2][4],
                                           ushort* __restrict__ Kl,
                                           ushort* __restrict__ Vl,
                                           f32x16 (&o)[4], float (&li)[2],
                                           int l5, int hi, int sr, int sc, int vbase) {
    bf16x8 k0 = *(const bf16x8*)kg;
    bf16x8 k1 = *(const bf16x8*)(kg + (size_t)32 * DIM);
    bf16x8 v0 = *(const bf16x8*)vg;
    bf16x8 v1 = *(const bf16x8*)(vg + (size_t)32 * M);
    __syncthreads();
    {   // tile 0 -> buf 0
        *(bf16x8*)(Kl + sr * 72 + sc) = k0;
        *(bf16x8*)(Kl + (sr + 32) * 72 + sc) = k1;
        union { bf16x8 v; uint2 h[2]; } cv;
        cv.v = v0;
        *(uint2*)(Vl + sr * 72 + vbase) = cv.h[0];
        *(uint2*)(Vl + sr * 72 + vbase + 8) = cv.h[1];
        cv.v = v1;
        *(uint2*)(Vl + (sr + 32) * 72 + vbase) = cv.h[0];
        *(uint2*)(Vl + (sr + 32) * 72 + vbase + 8) = cv.h[1];
    }
    if (nt > 1) {
        k0 = *(const bf16x8*)(kg + (size_t)64 * DIM);
        k1 = *(const bf16x8*)(kg + (size_t)96 * DIM);
        v0 = *(const bf16x8*)(vg + 64);
        v1 = *(const bf16x8*)(vg + (size_t)32 * M + 64);
    }
    for (int i = 0; i < nt; i++) {
        __syncthreads();
        if (i + 1 < nt) {
            ushort* Kb = Kl + ((i + 1) & 1) * (64 * 72);
            ushort* Vb = Vl + ((i + 1) & 1) * (64 * 72);
            *(bf16x8*)(Kb + sr * 72 + sc) = k0;
            *(bf16x8*)(Kb + (sr + 32) * 72 + sc) = k1;
            union { bf16x8 v; uint2 h[2]; } cv;
            cv.v = v0;
            *(uint2*)(Vb + sr * 72 + vbase) = cv.h[0];
            *(uint2*)(Vb + sr * 72 + vbase + 8) = cv.h[1];
            cv.v = v1;
            *(uint2*)(Vb + (sr + 32) * 72 + vbase) = cv.h[0];
            *(uint2*)(Vb + (sr + 32) * 72 + vbase + 8) = cv.h[1];
        }
        if (i + 2 < nt) {
            size_t off = (size_t)(i + 2) * 64;
            k0 = *(const bf16x8*)(kg + off * DIM);
            k1 = *(const bf16x8*)(kg + (off + 32) * DIM);
            v0 = *(const bf16x8*)(vg + off);
            v1 = *(const bf16x8*)(vg + (size_t)32 * M + off);
        }
        const ushort* Kc = Kl + (i & 1) * (64 * 72);
        const ushort* Vc = Vl + (i & 1) * (64 * 72);
#pragma unroll
        for (int c = 0; c < 2; c++) {
            bf16x8 kf[4];
#pragma unroll
            for (int kd = 0; kd < 4; kd++)
                kf[kd] = *(const bf16x8*)(Kc + (32 * c + l5) * 72 + kd * 16 + hi * 8);
            uint2 pq[2][4];
#pragma unroll
            for (int qh = 0; qh < 2; qh++) {
                f32x16 s;
#pragma unroll
                for (int ii = 0; ii < 16; ii++) s[ii] = 0.f;
#pragma unroll
                for (int kd = 0; kd < 4; kd++)
                    s = __builtin_amdgcn_mfma_f32_32x32x16_bf16(kf[kd], aq[qh][kd], s, 0, 0, 0);
#pragma unroll
                for (int m = 0; m < 4; m++) {
                    float p0 = fexp2(s[4 * m + 0]);
                    float p1 = fexp2(s[4 * m + 1]);
                    float p2 = fexp2(s[4 * m + 2]);
                    float p3 = fexp2(s[4 * m + 3]);
                    li[qh] += (p0 + p1) + (p2 + p3);
                    pq[qh][m].x = pk2bf(p0, p1);
                    pq[qh][m].y = pk2bf(p2, p3);
                }
            }
            // PV for this c's two k-slots; vf shared across both q-halves
#pragma unroll
            for (int kk = 0; kk < 2; kk++) {
                int kc = 2 * c + kk, m0 = 2 * kk;
                bf16x8 vf0 = *(const bf16x8*)(Vc + l5 * 72 + kc * 16 + hi * 8);
                bf16x8 vf1 = *(const bf16x8*)(Vc + (32 + l5) * 72 + kc * 16 + hi * 8);
#pragma unroll
                for (int qh = 0; qh < 2; qh++) {
                    union { bf16x8 v; uint u[4]; } w;
                    w.u[0] = pq[qh][m0].x;     w.u[1] = pq[qh][m0].y;
                    w.u[2] = pq[qh][m0 + 1].x; w.u[3] = pq[qh][m0 + 1].y;
                    o[qh * 2 + 0] = __builtin_amdgcn_mfma_f32_32x32x16_bf16(w.v, vf0, o[qh * 2 + 0], 0, 0, 0);
                    o[qh * 2 + 1] = __builtin_amdgcn_mfma_f32_32x32x16_bf16(w.v, vf1, o[qh * 2 + 1], 0, 0, 0);
                }
            }
        }
    }
}

// 512 threads: grp = ctx half, wave wg (0..3) owns 64 q-rows; block = 256 q.
// Exchange: TWO sequential rounds (one per q-half, FULLY UNROLLED -> static
// indices) of 34-float slots living strictly in grp1's dead staging region.
__global__ __launch_bounds__(512) void attn_kernel(const ushort* __restrict__ q,
                                                   const ushort* __restrict__ Ka,
                                                   const ushort* __restrict__ VTa,
                                                   const ushort* __restrict__ Ks,
                                                   const ushort* __restrict__ VTs,
                                                   ushort* __restrict__ y) {
    __shared__ ushort smem[2 * 18432];  // [grp][Kl 9216 | Vl 9216]
    int t = threadIdx.x;
    int grp = t >> 8;
    int tg = t & 255;
    int wg = tg >> 6;
    int ln = t & 63, l5 = ln & 31, hi = ln >> 5;
    ushort* Kl = smem + grp * 18432;
    ushort* Vl = Kl + 9216;
    float* osc = (float*)(smem + 18432);  // grp1 region ONLY: 256*34*4 B fits
    int h = blockIdx.y, bi = blockIdx.z;
    int q0 = blockIdx.x * 256 + wg * 64;
    bf16x8 aq[2][4];
#pragma unroll
    for (int qh = 0; qh < 2; qh++) {
        const ushort* qp = q + (size_t)(bi * NQ + q0 + qh * 32 + l5) * DIM + h * 64 + hi * 8;
#pragma unroll
        for (int kd = 0; kd < 4; kd++) aq[qh][kd] = *(const bf16x8*)(qp + kd * 16);
    }
    int sr = tg >> 3, sc = (tg & 7) * 8;
    int vbase = (sc >> 4) * 16 + ((sc >> 3) & 1) * 4;  // permuted V slot base

    f32x16 o[4];
#pragma unroll
    for (int k = 0; k < 4; k++)
#pragma unroll
        for (int i = 0; i < 16; i++) o[k][i] = 0.f;
    float li[2] = {0.f, 0.f};

    // audio (long) first: group grp handles ctx [grp*1024, grp*1024+1024)
    attn_ctx64(Ka + (size_t)bi * MA * DIM + (size_t)(grp * 1024 + sr) * DIM + h * 64 + sc,
               VTa + (size_t)bi * DIM * MA + (size_t)(h * 64 + sr) * MA + grp * 1024 + sc,
               MA, 16, aq, Kl, Vl, o, li, l5, hi, sr, sc, vbase);
    li[0] += __shfl_xor(li[0], 32);
    li[1] += __shfl_xor(li[1], 32);
    float yv[4][16];
    float* p = osc + tg * 34;
#pragma unroll
    for (int qh = 0; qh < 2; qh++) {   // FULL unroll: static qh (rule #20)
        __syncthreads();  // qh=0: staging reads done; qh=1: round-0 reads done
        if (grp) {
#pragma unroll
            for (int dn = 0; dn < 2; dn++)
#pragma unroll
                for (int r = 0; r < 8; r++)
                    *(float2*)(p + dn * 16 + 2 * r) =
                        (float2){o[qh * 2 + dn][2 * r], o[qh * 2 + dn][2 * r + 1]};
            p[32] = li[qh];
        }
        __syncthreads();  // partials visible
        if (!grp) {
#pragma unroll
            for (int dn = 0; dn < 2; dn++)
#pragma unroll
                for (int r = 0; r < 16; r++) o[qh * 2 + dn][r] += p[dn * 16 + r];
            li[qh] += p[32];
            float inv[16];
#pragma unroll
            for (int rg = 0; rg < 16; rg++)
                inv[rg] = 1.f / __shfl(li[qh], (rg & 3) + 8 * (rg >> 2) + 4 * hi);
#pragma unroll
            for (int dn = 0; dn < 2; dn++)
#pragma unroll
                for (int rg = 0; rg < 16; rg++)
                    yv[qh * 2 + dn][rg] = o[qh * 2 + dn][rg] * inv[rg];
        }
    }

#pragma unroll
    for (int k = 0; k < 4; k++)
#pragma unroll
        for (int i = 0; i < 16; i++) o[k][i] = 0.f;
    li[0] = li[1] = 0.f;
    // singer (short): group grp handles ctx [grp*128, grp*128+128)
    attn_ctx64(Ks + (size_t)bi * MS * DIM + (size_t)(grp * 128 + sr) * DIM + h * 64 + sc,
               VTs + (size_t)bi * DIM * MS + (size_t)(h * 64 + sr) * MS + grp * 128 + sc,
               MS, 2, aq, Kl, Vl, o, li, l5, hi, sr, sc, vbase);
    li[0] += __shfl_xor(li[0], 32);
    li[1] += __shfl_xor(li[1], 32);
#pragma unroll
    for (int qh = 0; qh < 2; qh++) {   // FULL unroll: static qh (rule #20)
        __syncthreads();  // qh=0: singer staging reads done; qh=1: round-0 done
        if (grp) {
#pragma unroll
            for (int dn = 0; dn < 2; dn++)
#pragma unroll
                for (int r = 0; r < 8; r++)
                    *(float2*)(p + dn * 16 + 2 * r) =
                        (float2){o[qh * 2 + dn][2 * r], o[qh * 2 + dn][2 * r + 1]};
            p[32] = li[qh];
        }
        __syncthreads();
        if (!grp) {
#pragma unroll
            for (int dn = 0; dn < 2; dn++)
#pragma unroll
                for (int r = 0; r < 16; r++) o[qh * 2 + dn][r] += p[dn * 16 + r];
            li[qh] += p[32];
            float inv[16];
#pragma unroll
            for (int rg = 0; rg < 16; rg++)
                inv[rg] = 1.f / __shfl(li[qh], (rg & 3) + 8 * (rg >> 2) + 4 * hi);
            // O: lane holds d = 32*dn + l5, q = q0 + qh*32 + crow(rg,hi)
#pragma unroll
            for (int dn = 0; dn < 2; dn++)
#pragma unroll
                for (int rg = 0; rg < 16; rg++) {
                    int qr = (rg & 3) + 8 * (rg >> 2) + 4 * hi;
                    float ov = yv[qh * 2 + dn][rg] + o[qh * 2 + dn][rg] * inv[rg];
                    y[(size_t)(bi * NQ + q0 + qh * 32 + qr) * DIM + h * 64 + 32 * dn + l5] = f2b(ov);
                }
        }
    }
}

extern "C" void kernel_launch(void* const* d_in, const int* in_sizes, int n_in,
                              void* d_out, int out_size, void* d_ws, size_t ws_size,
                              hipStream_t stream) {
    const float* x   = (const float*)d_in[0];
    const float* ac  = (const float*)d_in[1];
    const float* scx = (const float*)d_in[2];
    const float* Wq  = (const float*)d_in[3];
    const float* bq  = (const float*)d_in[4];
    const float* Wka = (const float*)d_in[5];
    const float* bka = (const float*)d_in[6];
    const float* Wva = (const float*)d_in[7];
    const float* bva = (const float*)d_in[8];
    const float* Wks = (const float*)d_in[9];
    const float* bks = (const float*)d_in[10];
    const float* Wvs = (const float*)d_in[11];
    const float* bvs = (const float*)d_in[12];
    const float* Wp  = (const float*)d_in[13];
    const float* bp  = (const float*)d_in[14];

    ushort* wb   = (ushort*)d_ws;         // contiguous cast dst:
    ushort* wqb  = wb;                    // [6 weights][xb][acb][scxb]
    ushort* wkab = wb + 262144;
    ushort* wvab = wb + 2 * 262144;
    ushort* wksb = wb + 3 * 262144;
    ushort* wvsb = wb + 4 * 262144;
    ushort* wpb  = wb + 5 * 262144;
    ushort* xb   = wb + 6 * 262144;       // [8192][512]
    ushort* acb  = xb + 4194304;          // [8192][512]
    ushort* scxb = acb + 4194304;         // [1024][512]
    ushort* qb   = scxb + 524288;         // [8192][512] prescaled q
    ushort* kab  = qb + 4194304;          // [8192][512]
    ushort* vta  = kab + 4194304;         // [4][512][2048] V^T
    ushort* ksb  = vta + 4194304;         // [1024][512]
    ushort* vts  = ksb + 524288;          // [4][512][256]  V^T
    ushort* yb   = xb;                    // alias: x dead after gemm_fused

    cast_all<<<10240, 256, 0, stream>>>(Wq, Wka, Wva, Wks, Wvs, Wp, x, ac, scx, wb);

    GD gq   = {xb,   wqb,  bq,  qb,  0, 0,               512,  64, 4,  0,   0, 1, 0, 0};
    GD gka  = {acb,  wkab, bka, kab, 0, 0,               512,  64, 4,  256, 0, 0, 0, 0};
    GD gvta = {wvab, acb,  bva, vta, 2048L * 512, 512L * 2048, 2048, 4, 16, 512, 1, 0, 0, 0};
    GD gks  = {scxb, wksb, bks, ksb, 0, 0,               512,  8,  4,  768, 0, 0, 0, 0};
    GD gvts = {wvsb, scxb, bvs, vts, 256L * 512, 512L * 256,   256,  4,  2,  800, 1, 0, 0, 0};
    gemm_fused<<<832, 256, 0, stream>>>(gq, gka, gvta, gks, gvts);

    attn_kernel<<<dim3(8, 8, 4), 512, 0, stream>>>(qb, kab, vta, ksb, vts, yb);

    GD gpr = {yb, wpb, bp, d_out, 0, 0, 512, 64, 4, 0, 0, 0, 1, 0};
    GD gnv = {nullptr, nullptr, nullptr, nullptr, 0, 0, 0, 1, 1, 1 << 30, 0, 0, 0, 0};
    gemm_fused<<<256, 256, 0, stream>>>(gpr, gnv, gnv, gnv, gnv);
}